// Round 2
// baseline (358.912 us; speedup 1.0000x reference)
//
#include <hip/hip_runtime.h>
#include <hip/hip_bf16.h>
#include <math.h>

#define B 16
#define S 200
#define IN 128
#define H 128
#define NK 11      // K+1 buckets
#define OUTN 10000
#define H4 512

// ---------------- embed gather: x[r,:] = table[seq[r],:] ----------------
__global__ void k_embed(const int* __restrict__ seq, const float* __restrict__ table,
                        float* __restrict__ x) {
    int r = blockIdx.x;        // 0..B*S-1
    int t = threadIdx.x;       // 0..127
    int s = seq[r];
    x[r * IN + t] = table[s * IN + t];
}

// ---------------- proj GEMMs: P[r,kb,:] = x[r,:] @ W[kb] ----------------
// grid (50, 22): y<11 -> time bucket y ; y>=11 -> dist bucket y-11
// block 512: thread = 4x4 micro-tile of a 64(row) x 128(col) tile
__global__ __launch_bounds__(512) void k_proj(
        const float* __restrict__ x, const float* __restrict__ tw,
        const float* __restrict__ dw, float* __restrict__ pt, float* __restrict__ pd) {
    __shared__ float xs[32][65];    // [k][r], padded
    __shared__ float wsm[32][128];  // [k][c]
    int which = blockIdx.y / NK;
    int kb = blockIdx.y % NK;
    const float* W = (which == 0 ? tw : dw) + kb * IN * H;
    float* P = (which == 0 ? pt : pd);
    int r0blk = blockIdx.x * 64;
    int tid = threadIdx.x;
    int tr = tid >> 5;          // 0..15 (row group)
    int tc = tid & 31;          // 0..31 (col group)
    int rr0 = tr * 4;

    float acc[4][4] = {{0.f}};
    for (int kk = 0; kk < IN; kk += 32) {
        {   // load x tile (transposed into xs[k][r])
            int r = tid >> 3;              // 0..63
            int kq = (tid & 7) * 4;        // 0,4,..,28
            float4 v = *reinterpret_cast<const float4*>(&x[(r0blk + r) * IN + kk + kq]);
            xs[kq + 0][r] = v.x; xs[kq + 1][r] = v.y;
            xs[kq + 2][r] = v.z; xs[kq + 3][r] = v.w;
        }
        #pragma unroll
        for (int i = 0; i < 2; ++i) {       // load W chunk [32][128]
            int f = tid + i * 512;          // float4 index 0..1023
            int k = f >> 5; int c4 = f & 31;
            *reinterpret_cast<float4*>(&wsm[k][c4 * 4]) =
                *reinterpret_cast<const float4*>(&W[(kk + k) * H + c4 * 4]);
        }
        __syncthreads();
        #pragma unroll
        for (int k = 0; k < 32; ++k) {
            float a0 = xs[k][rr0 + 0], a1 = xs[k][rr0 + 1];
            float a2 = xs[k][rr0 + 2], a3 = xs[k][rr0 + 3];
            float4 w = *reinterpret_cast<const float4*>(&wsm[k][tc * 4]);
            acc[0][0] += a0 * w.x; acc[0][1] += a0 * w.y; acc[0][2] += a0 * w.z; acc[0][3] += a0 * w.w;
            acc[1][0] += a1 * w.x; acc[1][1] += a1 * w.y; acc[1][2] += a1 * w.z; acc[1][3] += a1 * w.w;
            acc[2][0] += a2 * w.x; acc[2][1] += a2 * w.y; acc[2][2] += a2 * w.z; acc[2][3] += a2 * w.w;
            acc[3][0] += a3 * w.x; acc[3][1] += a3 * w.y; acc[3][2] += a3 * w.z; acc[3][3] += a3 * w.w;
        }
        __syncthreads();
    }
    #pragma unroll
    for (int i = 0; i < 4; ++i) {
        int r = r0blk + rr0 + i;
        float4 v = make_float4(acc[i][0], acc[i][1], acc[i][2], acc[i][3]);
        *reinterpret_cast<float4*>(&P[(r * NK + kb) * H + tc * 4]) = v;
    }
}

// ---------------- X[b,i,:] = 0.5 * sum_j (P_t[b,j,tk] + P_d[b,j,dk]) ----------------
// grid B*S, block 128 (one thread per h)
__global__ void k_xsum(const float* __restrict__ pt, const float* __restrict__ pd,
                       const int* __restrict__ length, const float* __restrict__ ts,
                       const float* __restrict__ lat, const float* __restrict__ lng,
                       float* __restrict__ X) {
    int bi = blockIdx.x;
    int b = bi / S, i = bi % S;
    int len = length[b];
    if (i >= len) return;
    __shared__ float sts[S], sla[S], sln[S];
    int t = threadIdx.x;
    for (int j = t; j < S; j += 128) {
        sts[j] = ts[b * S + j]; sla[j] = lat[b * S + j]; sln[j] = lng[b * S + j];
    }
    __syncthreads();
    float ti = sts[i], lai = sla[i], lni = sln[i];
    float acc = 0.f;
    for (int j = 0; j <= i; ++j) {
        float td = ti - sts[j];
        if (td < 0.f || td > 1.f) continue;      // time window (td>=0 guaranteed by sort)
        int tk = (int)floorf(fminf(fmaxf(td, 0.f), 1.f) * 10.f); if (tk > 10) tk = 10;
        float dx = lai - sla[j], dy = lni - sln[j];
        float dist = sqrtf(dx * dx + dy * dy);
        int dk = (int)floorf(fminf(fmaxf(dist, 0.f), 1.f) * 10.f); if (dk > 10) dk = 10;
        acc += pt[((b * S + j) * NK + tk) * H + t] + pd[((b * S + j) * NK + dk) * H + t];
    }
    X[(b * S + i) * H + t] = 0.5f * acc;
}

// ---------------- RNN: h_i = sigmoid(X_i + h_{i-1} @ Wh), output h[len-1] ----------------
// grid B, block 256: tid&127 = output h', tid>>7 = k-half; Wh half-column in registers
__global__ __launch_bounds__(256) void k_rnn(const float* __restrict__ X,
        const float* __restrict__ Wh, const int* __restrict__ length,
        float* __restrict__ hpre) {
    __shared__ float hcur[H];
    __shared__ float red[H];
    int b = blockIdx.x;
    int len = length[b];
    int tid = threadIdx.x;
    int hh = tid & 127;
    int g = tid >> 7;
    float w[64];
    #pragma unroll
    for (int k = 0; k < 64; ++k) w[k] = Wh[(g * 64 + k) * H + hh];
    if (tid < H) hcur[tid] = 0.f;
    __syncthreads();
    const float* Xb = X + b * S * H;
    float xn = (g == 0) ? Xb[hh] : 0.f;
    for (int i = 0; i < len; ++i) {
        float xc = xn;
        if (g == 0 && i + 1 < len) xn = Xb[(i + 1) * H + hh];
        float p0 = 0.f, p1 = 0.f, p2 = 0.f, p3 = 0.f;
        const float* hbase = &hcur[g * 64];
        #pragma unroll
        for (int kq = 0; kq < 16; ++kq) {
            float4 hv = *reinterpret_cast<const float4*>(&hbase[kq * 4]);
            p0 += hv.x * w[kq * 4 + 0];
            p1 += hv.y * w[kq * 4 + 1];
            p2 += hv.z * w[kq * 4 + 2];
            p3 += hv.w * w[kq * 4 + 3];
        }
        float p = (p0 + p1) + (p2 + p3);
        if (g) red[hh] = p;
        __syncthreads();
        if (!g) {
            float s = xc + p + red[hh];
            hcur[hh] = 1.f / (1.f + expf(-s));
        }
        __syncthreads();
    }
    if (tid < H) hpre[b * H + tid] = hcur[tid];
}

// ---------------- FC1: t1[b,o] = tanh(hpre[b,:] @ W1[:,o] + b1[o]) ----------------
__global__ void k_fc1(const float* __restrict__ hpre, const float* __restrict__ W1,
                      const float* __restrict__ b1, float* __restrict__ t1) {
    __shared__ float hs[H];
    int b = blockIdx.x, o = threadIdx.x;  // block 512
    if (o < H) hs[o] = hpre[b * H + o];
    __syncthreads();
    float acc = b1[o];
    #pragma unroll 4
    for (int k = 0; k < H; ++k) acc += hs[k] * W1[k * H4 + o];
    t1[b * H4 + o] = tanhf(acc);
}

// ---------------- FC2: out[b,o] = t1[b,:] @ W2[:,o] + b2[o] ----------------
// grid ceil(OUTN/64), block 256: o = o0 + tid&63, bq = tid>>6 handles b = bq*4..bq*4+3
__global__ __launch_bounds__(256) void k_fc2(const float* __restrict__ t1,
        const float* __restrict__ W2, const float* __restrict__ b2,
        float* __restrict__ out) {
    __shared__ float tls[H4 * B];   // [k][b] layout, 32KB
    int tid = threadIdx.x;
    int o = blockIdx.x * 64 + (tid & 63);
    int bq = tid >> 6;              // 0..3
    for (int idx = tid; idx < H4 * B; idx += 256) {
        int k = idx >> 4, bb = idx & 15;
        tls[idx] = t1[bb * H4 + k];
    }
    __syncthreads();
    if (o >= OUTN) return;
    float a0 = 0.f, a1 = 0.f, a2 = 0.f, a3 = 0.f;
    for (int k = 0; k < H4; ++k) {
        float wv = W2[k * OUTN + o];
        const float* tk = &tls[k * 16 + bq * 4];
        a0 += wv * tk[0]; a1 += wv * tk[1]; a2 += wv * tk[2]; a3 += wv * tk[3];
    }
    float bb2 = b2[o];
    out[(bq * 4 + 0) * OUTN + o] = a0 + bb2;
    out[(bq * 4 + 1) * OUTN + o] = a1 + bb2;
    out[(bq * 4 + 2) * OUTN + o] = a2 + bb2;
    out[(bq * 4 + 3) * OUTN + o] = a3 + bb2;
}

extern "C" void kernel_launch(void* const* d_in, const int* in_sizes, int n_in,
                              void* d_out, int out_size, void* d_ws, size_t ws_size,
                              hipStream_t stream) {
    const int*   seq    = (const int*)d_in[0];
    const int*   length = (const int*)d_in[1];
    const float* ts     = (const float*)d_in[2];
    const float* lat    = (const float*)d_in[3];
    const float* lng    = (const float*)d_in[4];
    const float* table  = (const float*)d_in[5];
    const float* tw     = (const float*)d_in[6];
    const float* dw     = (const float*)d_in[7];
    const float* wh     = (const float*)d_in[8];
    const float* W1     = (const float*)d_in[9];
    const float* b1     = (const float*)d_in[10];
    const float* W2     = (const float*)d_in[11];
    const float* b2     = (const float*)d_in[12];
    float* out = (float*)d_out;

    float* wsf  = (float*)d_ws;
    float* x    = wsf;                       // B*S*IN           = 409600
    float* pt   = x  + B * S * IN;           // B*S*NK*H         = 4505600
    float* pd   = pt + B * S * NK * H;       // B*S*NK*H         = 4505600
    float* X    = pd + B * S * NK * H;       // B*S*H            = 409600
    float* hpre = X  + B * S * H;            // B*H              = 2048
    float* t1   = hpre + B * H;              // B*H4             = 8192

    k_embed<<<B * S, IN, 0, stream>>>(seq, table, x);
    k_proj<<<dim3((B * S) / 64, 2 * NK), 512, 0, stream>>>(x, tw, dw, pt, pd);
    k_xsum<<<B * S, H, 0, stream>>>(pt, pd, length, ts, lat, lng, X);
    k_rnn<<<B, 256, 0, stream>>>(X, wh, length, hpre);
    k_fc1<<<B, H4, 0, stream>>>(hpre, W1, b1, t1);
    k_fc2<<<(OUTN + 63) / 64, 256, 0, stream>>>(t1, W2, b2, out);
}

// Round 6
// 349.465 us; speedup vs baseline: 1.0270x; 1.0270x over previous
//
#include <hip/hip_runtime.h>
#include <hip/hip_bf16.h>
#include <math.h>

#define B 16
#define S 200
#define IN 128
#define H 128
#define NK 11      // K+1 buckets
#define OUTN 10000
#define H4 512

// ---------------- proj GEMMs (embed fused): P[r,kb,:] = table[seq[r],:] @ W[kb] ----------------
// grid (50, 22): y<11 -> time bucket y ; y>=11 -> dist bucket y-11
// block 512: thread = 4x4 micro-tile of a 64(row) x 128(col) tile
// blocks whose 64 rows are all i >= len[b] are skipped (their P rows are never read)
__global__ __launch_bounds__(512) void k_proj(
        const int* __restrict__ seq, const float* __restrict__ table,
        const int* __restrict__ length,
        const float* __restrict__ tw, const float* __restrict__ dw,
        float* __restrict__ pt, float* __restrict__ pd) {
    __shared__ float xs[32][68];    // [k][r], padded so xs[k][4*tr] is 16B aligned
    __shared__ float wsm[32][128];  // [k][c]
    __shared__ int sneed;
    int tid = threadIdx.x;
    int r0blk = blockIdx.x * 64;
    if (tid == 0) sneed = 0;
    __syncthreads();
    if (tid < 64) {
        int r = r0blk + tid;
        int bb = r / S, ii = r - bb * S;
        if (ii < length[bb]) sneed = 1;   // benign same-value race
    }
    __syncthreads();
    if (!sneed) return;

    int which = blockIdx.y / NK;
    int kb = blockIdx.y % NK;
    const float* W = (which == 0 ? tw : dw) + kb * IN * H;
    float* P = (which == 0 ? pt : pd);
    int tr = tid >> 5;          // 0..15 (row group)
    int tc = tid & 31;          // 0..31 (col group)
    int rr0 = tr * 4;

    float acc[4][4] = {{0.f}};
    for (int kk = 0; kk < IN; kk += 32) {
        {   // load x tile via embed gather (transposed into xs[k][r])
            int r = tid >> 3;              // 0..63
            int kq = (tid & 7) * 4;        // 0,4,..,28
            int sv = seq[r0blk + r];
            float4 v = *reinterpret_cast<const float4*>(&table[sv * IN + kk + kq]);
            xs[kq + 0][r] = v.x; xs[kq + 1][r] = v.y;
            xs[kq + 2][r] = v.z; xs[kq + 3][r] = v.w;
        }
        #pragma unroll
        for (int i = 0; i < 2; ++i) {       // load W chunk [32][128]
            int f = tid + i * 512;          // float4 index 0..1023
            int k = f >> 5; int c4 = f & 31;
            *reinterpret_cast<float4*>(&wsm[k][c4 * 4]) =
                *reinterpret_cast<const float4*>(&W[(kk + k) * H + c4 * 4]);
        }
        __syncthreads();
        #pragma unroll
        for (int k = 0; k < 32; ++k) {
            float4 a = *reinterpret_cast<const float4*>(&xs[k][rr0]);
            float4 w = *reinterpret_cast<const float4*>(&wsm[k][tc * 4]);
            acc[0][0] += a.x * w.x; acc[0][1] += a.x * w.y; acc[0][2] += a.x * w.z; acc[0][3] += a.x * w.w;
            acc[1][0] += a.y * w.x; acc[1][1] += a.y * w.y; acc[1][2] += a.y * w.z; acc[1][3] += a.y * w.w;
            acc[2][0] += a.z * w.x; acc[2][1] += a.z * w.y; acc[2][2] += a.z * w.z; acc[2][3] += a.z * w.w;
            acc[3][0] += a.w * w.x; acc[3][1] += a.w * w.y; acc[3][2] += a.w * w.z; acc[3][3] += a.w * w.w;
        }
        __syncthreads();
    }
    #pragma unroll
    for (int i = 0; i < 4; ++i) {
        int r = r0blk + rr0 + i;
        float4 v = make_float4(acc[i][0], acc[i][1], acc[i][2], acc[i][3]);
        *reinterpret_cast<float4*>(&P[(r * NK + kb) * H + tc * 4]) = v;
    }
}

// ---------------- X[b,i,:] = 0.5 * sum_j (P_t[b,j,tk] + P_d[b,j,dk]) ----------------
// grid B*S, block 128 (one thread per h)
__global__ void k_xsum(const float* __restrict__ pt, const float* __restrict__ pd,
                       const int* __restrict__ length, const float* __restrict__ ts,
                       const float* __restrict__ lat, const float* __restrict__ lng,
                       float* __restrict__ X) {
    int bi = blockIdx.x;
    int b = bi / S, i = bi % S;
    int len = length[b];
    if (i >= len) return;
    __shared__ float sts[S], sla[S], sln[S];
    int t = threadIdx.x;
    for (int j = t; j < S; j += 128) {
        sts[j] = ts[b * S + j]; sla[j] = lat[b * S + j]; sln[j] = lng[b * S + j];
    }
    __syncthreads();
    float ti = sts[i], lai = sla[i], lni = sln[i];
    float acc = 0.f;
    for (int j = 0; j <= i; ++j) {
        float td = ti - sts[j];
        if (td < 0.f || td > 1.f) continue;      // block-uniform branch
        int tk = (int)floorf(fminf(fmaxf(td, 0.f), 1.f) * 10.f); if (tk > 10) tk = 10;
        float dx = lai - sla[j], dy = lni - sln[j];
        float dist = sqrtf(dx * dx + dy * dy);
        int dk = (int)floorf(fminf(fmaxf(dist, 0.f), 1.f) * 10.f); if (dk > 10) dk = 10;
        acc += pt[((b * S + j) * NK + tk) * H + t] + pd[((b * S + j) * NK + dk) * H + t];
    }
    X[(b * S + i) * H + t] = 0.5f * acc;
}

// ---------------- RNN: h_i = sigmoid(X_i + h_{i-1} @ Wh), output h[len-1] ----------------
// grid B, block 512 (8 waves). lane = oo*4+kg: output o = wave*16+oo, k-range kg*32..+32.
// 4-way k-split reduced via 2x shfl_xor; ping-pong h buffer -> ONE barrier per step.
// LDS read addresses staggered by (it^kg) to avoid 4-way bank aliasing; weight registers
// loaded in matching order so all register indices stay compile-time (no scratch).
__global__ __launch_bounds__(512) void k_rnn(const float* __restrict__ X,
        const float* __restrict__ Wh, const int* __restrict__ length,
        float* __restrict__ hpre) {
    __shared__ float hbuf[2][H];
    int b = blockIdx.x;
    int len = length[b];
    int tid = threadIdx.x;
    int w8 = tid >> 6;          // wave 0..7
    int lane = tid & 63;
    int oo = lane >> 2;         // 0..15
    int kg = lane & 3;          // 0..3
    int o = w8 * 16 + oo;       // output index 0..127
    float wreg[32];
    #pragma unroll
    for (int it = 0; it < 8; ++it) {
        int kk = kg * 32 + ((it ^ kg) & 7) * 4;
        #pragma unroll
        for (int q = 0; q < 4; ++q)
            wreg[it * 4 + q] = Wh[(kk + q) * H + o];
    }
    if (tid < H) hbuf[0][tid] = 0.f;
    __syncthreads();
    const float* Xb = X + b * S * H;
    float xn = (kg == 0) ? Xb[o] : 0.f;   // len >= 1 so X[b,0,:] is valid
    float hlast = 0.f;
    int cur = 0;
    for (int i = 0; i < len; ++i) {
        float xc = xn;
        if (kg == 0 && i + 1 < len) xn = Xb[(i + 1) * H + o];
        const float* hb = &hbuf[cur][kg * 32];
        float p0 = 0.f, p1 = 0.f, p2 = 0.f, p3 = 0.f;
        #pragma unroll
        for (int it = 0; it < 8; ++it) {
            float4 hv = *reinterpret_cast<const float4*>(&hb[((it ^ kg) & 7) * 4]);
            p0 += hv.x * wreg[it * 4 + 0];
            p1 += hv.y * wreg[it * 4 + 1];
            p2 += hv.z * wreg[it * 4 + 2];
            p3 += hv.w * wreg[it * 4 + 3];
        }
        float p = (p0 + p1) + (p2 + p3);
        p += __shfl_xor(p, 1);
        p += __shfl_xor(p, 2);
        if (kg == 0) {
            float hn = 1.f / (1.f + __expf(-(xc + p)));
            hbuf[cur ^ 1][o] = hn;
            hlast = hn;
        }
        __syncthreads();
        cur ^= 1;
    }
    if (kg == 0) hpre[b * H + o] = hlast;
}

// ---------------- FC1: t1[b,o] = tanh(hpre[b,:] @ W1[:,o] + b1[o]) ----------------
__global__ void k_fc1(const float* __restrict__ hpre, const float* __restrict__ W1,
                      const float* __restrict__ b1, float* __restrict__ t1) {
    __shared__ float hs[H];
    int b = blockIdx.x, o = threadIdx.x;  // block 512
    if (o < H) hs[o] = hpre[b * H + o];
    __syncthreads();
    float acc = b1[o];
    #pragma unroll 4
    for (int k = 0; k < H; ++k) acc += hs[k] * W1[k * H4 + o];
    t1[b * H4 + o] = tanhf(acc);
}

// ---------------- FC2: out[b,o] = t1[b,:] @ W2[:,o] + b2[o] ----------------
__global__ __launch_bounds__(256) void k_fc2(const float* __restrict__ t1,
        const float* __restrict__ W2, const float* __restrict__ b2,
        float* __restrict__ out) {
    __shared__ float tls[H4 * B];   // [k][b] layout, 32KB
    int tid = threadIdx.x;
    int o = blockIdx.x * 64 + (tid & 63);
    int bq = tid >> 6;              // 0..3
    for (int idx = tid; idx < H4 * B; idx += 256) {
        int k = idx >> 4, bb = idx & 15;
        tls[idx] = t1[bb * H4 + k];
    }
    __syncthreads();
    if (o >= OUTN) return;
    float a0 = 0.f, a1 = 0.f, a2 = 0.f, a3 = 0.f;
    for (int k = 0; k < H4; ++k) {
        float wv = W2[k * OUTN + o];
        const float* tk = &tls[k * 16 + bq * 4];
        a0 += wv * tk[0]; a1 += wv * tk[1]; a2 += wv * tk[2]; a3 += wv * tk[3];
    }
    float bb2 = b2[o];
    out[(bq * 4 + 0) * OUTN + o] = a0 + bb2;
    out[(bq * 4 + 1) * OUTN + o] = a1 + bb2;
    out[(bq * 4 + 2) * OUTN + o] = a2 + bb2;
    out[(bq * 4 + 3) * OUTN + o] = a3 + bb2;
}

extern "C" void kernel_launch(void* const* d_in, const int* in_sizes, int n_in,
                              void* d_out, int out_size, void* d_ws, size_t ws_size,
                              hipStream_t stream) {
    const int*   seq    = (const int*)d_in[0];
    const int*   length = (const int*)d_in[1];
    const float* ts     = (const float*)d_in[2];
    const float* lat    = (const float*)d_in[3];
    const float* lng    = (const float*)d_in[4];
    const float* table  = (const float*)d_in[5];
    const float* tw     = (const float*)d_in[6];
    const float* dw     = (const float*)d_in[7];
    const float* wh     = (const float*)d_in[8];
    const float* W1     = (const float*)d_in[9];
    const float* b1     = (const float*)d_in[10];
    const float* W2     = (const float*)d_in[11];
    const float* b2     = (const float*)d_in[12];
    float* out = (float*)d_out;

    float* wsf  = (float*)d_ws;
    float* pt   = wsf;                       // B*S*NK*H = 4505600
    float* pd   = pt + B * S * NK * H;       // B*S*NK*H = 4505600
    float* X    = pd + B * S * NK * H;       // B*S*H    = 409600
    float* hpre = X  + B * S * H;            // B*H      = 2048
    float* t1   = hpre + B * H;              // B*H4     = 8192

    k_proj<<<dim3((B * S) / 64, 2 * NK), 512, 0, stream>>>(seq, table, length, tw, dw, pt, pd);
    k_xsum<<<B * S, H, 0, stream>>>(pt, pd, length, ts, lat, lng, X);
    k_rnn<<<B, 512, 0, stream>>>(X, wh, length, hpre);
    k_fc1<<<B, H4, 0, stream>>>(hpre, W1, b1, t1);
    k_fc2<<<(OUTN + 63) / 64, 256, 0, stream>>>(t1, W2, b2, out);
}

// Round 11
// 283.522 us; speedup vs baseline: 1.2659x; 1.2326x over previous
//
#include <hip/hip_runtime.h>
#include <hip/hip_bf16.h>
#include <math.h>

#define B 16
#define S 200
#define IN 128
#define H 128
#define NK 11      // K+1 buckets
#define OUTN 10000
#define H4 512

// ---------------- proj GEMMs (embed fused): P[r,kb,:] = table[seq[r],:] @ W[kb] ----------------
__global__ __launch_bounds__(512) void k_proj(
        const int* __restrict__ seq, const float* __restrict__ table,
        const int* __restrict__ length,
        const float* __restrict__ tw, const float* __restrict__ dw,
        float* __restrict__ pt, float* __restrict__ pd) {
    __shared__ float xs[32][68];    // [k][r], padded so xs[k][4*tr] is 16B aligned
    __shared__ float wsm[32][128];  // [k][c]
    __shared__ int sneed;
    int tid = threadIdx.x;
    int r0blk = blockIdx.x * 64;
    if (tid == 0) sneed = 0;
    __syncthreads();
    if (tid < 64) {
        int r = r0blk + tid;
        int bb = r / S, ii = r - bb * S;
        if (ii < length[bb]) sneed = 1;   // benign same-value race
    }
    __syncthreads();
    if (!sneed) return;

    int which = blockIdx.y / NK;
    int kb = blockIdx.y % NK;
    const float* W = (which == 0 ? tw : dw) + kb * IN * H;
    float* P = (which == 0 ? pt : pd);
    int tr = tid >> 5;          // 0..15 (row group)
    int tc = tid & 31;          // 0..31 (col group)
    int rr0 = tr * 4;

    float acc[4][4] = {{0.f}};
    for (int kk = 0; kk < IN; kk += 32) {
        {   // load x tile via embed gather (transposed into xs[k][r])
            int r = tid >> 3;              // 0..63
            int kq = (tid & 7) * 4;        // 0,4,..,28
            int sv = seq[r0blk + r];
            float4 v = *reinterpret_cast<const float4*>(&table[sv * IN + kk + kq]);
            xs[kq + 0][r] = v.x; xs[kq + 1][r] = v.y;
            xs[kq + 2][r] = v.z; xs[kq + 3][r] = v.w;
        }
        #pragma unroll
        for (int i = 0; i < 2; ++i) {       // load W chunk [32][128]
            int f = tid + i * 512;          // float4 index 0..1023
            int k = f >> 5; int c4 = f & 31;
            *reinterpret_cast<float4*>(&wsm[k][c4 * 4]) =
                *reinterpret_cast<const float4*>(&W[(kk + k) * H + c4 * 4]);
        }
        __syncthreads();
        #pragma unroll
        for (int k = 0; k < 32; ++k) {
            float4 a = *reinterpret_cast<const float4*>(&xs[k][rr0]);
            float4 w = *reinterpret_cast<const float4*>(&wsm[k][tc * 4]);
            acc[0][0] += a.x * w.x; acc[0][1] += a.x * w.y; acc[0][2] += a.x * w.z; acc[0][3] += a.x * w.w;
            acc[1][0] += a.y * w.x; acc[1][1] += a.y * w.y; acc[1][2] += a.y * w.z; acc[1][3] += a.y * w.w;
            acc[2][0] += a.z * w.x; acc[2][1] += a.z * w.y; acc[2][2] += a.z * w.z; acc[2][3] += a.z * w.w;
            acc[3][0] += a.w * w.x; acc[3][1] += a.w * w.y; acc[3][2] += a.w * w.z; acc[3][3] += a.w * w.w;
        }
        __syncthreads();
    }
    #pragma unroll
    for (int i = 0; i < 4; ++i) {
        int r = r0blk + rr0 + i;
        float4 v = make_float4(acc[i][0], acc[i][1], acc[i][2], acc[i][3]);
        *reinterpret_cast<float4*>(&P[(r * NK + kb) * H + tc * 4]) = v;
    }
}

// ---------------- X[b,i,:] = 0.5 * sum_j (P_t[b,j,tk] + P_d[b,j,dk]) ----------------
// grid 3200 XCD-swizzled, block 512: jg = tid>>5 (16-way j-split), c = tid&31 (float4 over H).
// Serial chain cut 200 -> <=13 iters/group; float4 loads (16B/lane); LDS tree-reduce of 16 partials.
__global__ __launch_bounds__(512) void k_xsum(const float* __restrict__ pt, const float* __restrict__ pd,
                       const int* __restrict__ length, const float* __restrict__ ts,
                       const float* __restrict__ lat, const float* __restrict__ lng,
                       float* __restrict__ X) {
    int wg = blockIdx.x;
    int idx = wg >> 3;                    // 0..399
    int b = (wg & 7) + 8 * (idx / S);     // XCD x serves batches {x, x+8}: L2 locality
    int i = idx % S;
    int len = length[b];
    if (i >= len) return;
    __shared__ float sts[S], sla[S], sln[S];
    __shared__ float psum[16][128];
    int tid = threadIdx.x;
    int jg = tid >> 5, c = tid & 31;
    if (tid < S) {
        sts[tid] = ts[b * S + tid]; sla[tid] = lat[b * S + tid]; sln[tid] = lng[b * S + tid];
    }
    __syncthreads();
    float ti = sts[i], lai = sla[i], lni = sln[i];
    float4 at = make_float4(0.f, 0.f, 0.f, 0.f);
    float4 ad = make_float4(0.f, 0.f, 0.f, 0.f);
    const float* ptb = pt + (b * S) * NK * H;
    const float* pdb = pd + (b * S) * NK * H;
    for (int j = jg; j <= i; j += 16) {       // interleaved for group load balance
        float td = ti - sts[j];
        if (td < 0.f || td > 1.f) continue;   // exact reference window (uniform per 32-lane group)
        int tk = (int)(td * 10.f); if (tk > 10) tk = 10;    // td>=0: cast==floor
        float dx = lai - sla[j], dy = lni - sln[j];
        float dist = sqrtf(dx * dx + dy * dy);
        int dk = (int)(dist * 10.f); if (dk > 10) dk = 10;  // matches clip->*10->floor
        float4 vt = *((const float4*)&ptb[(j * NK + tk) * H] + c);
        float4 vd = *((const float4*)&pdb[(j * NK + dk) * H] + c);
        at.x += vt.x; at.y += vt.y; at.z += vt.z; at.w += vt.w;
        ad.x += vd.x; ad.y += vd.y; ad.z += vd.z; ad.w += vd.w;
    }
    float4 s4 = make_float4(at.x + ad.x, at.y + ad.y, at.z + ad.z, at.w + ad.w);
    *reinterpret_cast<float4*>(&psum[jg][c * 4]) = s4;
    __syncthreads();
    if (tid < H) {
        float s = 0.f;
        #pragma unroll
        for (int g = 0; g < 16; ++g) s += psum[g][tid];
        X[(b * S + i) * H + tid] = 0.5f * s;
    }
}

// ---------------- RNN: h_i = sigmoid(X_i + h_{i-1} @ Wh), output h[len-1] ----------------
__global__ __launch_bounds__(512) void k_rnn(const float* __restrict__ X,
        const float* __restrict__ Wh, const int* __restrict__ length,
        float* __restrict__ hpre) {
    __shared__ float hbuf[2][H];
    int b = blockIdx.x;
    int len = length[b];
    int tid = threadIdx.x;
    int w8 = tid >> 6;          // wave 0..7
    int lane = tid & 63;
    int oo = lane >> 2;         // 0..15
    int kg = lane & 3;          // 0..3
    int o = w8 * 16 + oo;       // output index 0..127
    float wreg[32];
    #pragma unroll
    for (int it = 0; it < 8; ++it) {
        int kk = kg * 32 + ((it ^ kg) & 7) * 4;
        #pragma unroll
        for (int q = 0; q < 4; ++q)
            wreg[it * 4 + q] = Wh[(kk + q) * H + o];
    }
    if (tid < H) hbuf[0][tid] = 0.f;
    __syncthreads();
    const float* Xb = X + b * S * H;
    float xn = (kg == 0) ? Xb[o] : 0.f;   // len >= 1 so X[b,0,:] is valid
    float hlast = 0.f;
    int cur = 0;
    for (int i = 0; i < len; ++i) {
        float xc = xn;
        if (kg == 0 && i + 1 < len) xn = Xb[(i + 1) * H + o];
        const float* hb = &hbuf[cur][kg * 32];
        float p0 = 0.f, p1 = 0.f, p2 = 0.f, p3 = 0.f;
        #pragma unroll
        for (int it = 0; it < 8; ++it) {
            float4 hv = *reinterpret_cast<const float4*>(&hb[((it ^ kg) & 7) * 4]);
            p0 += hv.x * wreg[it * 4 + 0];
            p1 += hv.y * wreg[it * 4 + 1];
            p2 += hv.z * wreg[it * 4 + 2];
            p3 += hv.w * wreg[it * 4 + 3];
        }
        float p = (p0 + p1) + (p2 + p3);
        p += __shfl_xor(p, 1);
        p += __shfl_xor(p, 2);
        if (kg == 0) {
            float hn = 1.f / (1.f + __expf(-(xc + p)));
            hbuf[cur ^ 1][o] = hn;
            hlast = hn;
        }
        __syncthreads();
        cur ^= 1;
    }
    if (kg == 0) hpre[b * H + o] = hlast;
}

// ---------------- FC1: t1[b,o] = tanh(hpre[b,:] @ W1[:,o] + b1[o]) ----------------
__global__ void k_fc1(const float* __restrict__ hpre, const float* __restrict__ W1,
                      const float* __restrict__ b1, float* __restrict__ t1) {
    __shared__ float hs[H];
    int b = blockIdx.x, o = threadIdx.x;  // block 512
    if (o < H) hs[o] = hpre[b * H + o];
    __syncthreads();
    float acc = b1[o];
    #pragma unroll 4
    for (int k = 0; k < H; ++k) acc += hs[k] * W1[k * H4 + o];
    t1[b * H4 + o] = tanhf(acc);
}

// ---------------- FC2: out[b,o] = t1[b,:] @ W2[:,o] + b2[o] ----------------
__global__ __launch_bounds__(256) void k_fc2(const float* __restrict__ t1,
        const float* __restrict__ W2, const float* __restrict__ b2,
        float* __restrict__ out) {
    __shared__ float tls[H4 * B];   // [k][b] layout, 32KB
    int tid = threadIdx.x;
    int o = blockIdx.x * 64 + (tid & 63);
    int bq = tid >> 6;              // 0..3
    for (int idx = tid; idx < H4 * B; idx += 256) {
        int k = idx >> 4, bb = idx & 15;
        tls[idx] = t1[bb * H4 + k];
    }
    __syncthreads();
    if (o >= OUTN) return;
    float a0 = 0.f, a1 = 0.f, a2 = 0.f, a3 = 0.f;
    for (int k = 0; k < H4; ++k) {
        float wv = W2[k * OUTN + o];
        const float* tk = &tls[k * 16 + bq * 4];
        a0 += wv * tk[0]; a1 += wv * tk[1]; a2 += wv * tk[2]; a3 += wv * tk[3];
    }
    float bb2 = b2[o];
    out[(bq * 4 + 0) * OUTN + o] = a0 + bb2;
    out[(bq * 4 + 1) * OUTN + o] = a1 + bb2;
    out[(bq * 4 + 2) * OUTN + o] = a2 + bb2;
    out[(bq * 4 + 3) * OUTN + o] = a3 + bb2;
}

extern "C" void kernel_launch(void* const* d_in, const int* in_sizes, int n_in,
                              void* d_out, int out_size, void* d_ws, size_t ws_size,
                              hipStream_t stream) {
    const int*   seq    = (const int*)d_in[0];
    const int*   length = (const int*)d_in[1];
    const float* ts     = (const float*)d_in[2];
    const float* lat    = (const float*)d_in[3];
    const float* lng    = (const float*)d_in[4];
    const float* table  = (const float*)d_in[5];
    const float* tw     = (const float*)d_in[6];
    const float* dw     = (const float*)d_in[7];
    const float* wh     = (const float*)d_in[8];
    const float* W1     = (const float*)d_in[9];
    const float* b1     = (const float*)d_in[10];
    const float* W2     = (const float*)d_in[11];
    const float* b2     = (const float*)d_in[12];
    float* out = (float*)d_out;

    float* wsf  = (float*)d_ws;
    float* pt   = wsf;                       // B*S*NK*H = 4505600
    float* pd   = pt + B * S * NK * H;       // B*S*NK*H = 4505600
    float* X    = pd + B * S * NK * H;       // B*S*H    = 409600
    float* hpre = X  + B * S * H;            // B*H      = 2048
    float* t1   = hpre + B * H;              // B*H4     = 8192

    k_proj<<<dim3((B * S) / 64, 2 * NK), 512, 0, stream>>>(seq, table, length, tw, dw, pt, pd);
    k_xsum<<<B * S, 512, 0, stream>>>(pt, pd, length, ts, lat, lng, X);
    k_rnn<<<B, 512, 0, stream>>>(X, wh, length, hpre);
    k_fc1<<<B, H4, 0, stream>>>(hpre, W1, b1, t1);
    k_fc2<<<(OUTN + 63) / 64, 256, 0, stream>>>(t1, W2, b2, out);
}

// Round 12
// 249.177 us; speedup vs baseline: 1.4404x; 1.1378x over previous
//
#include <hip/hip_runtime.h>
#include <hip/hip_bf16.h>
#include <math.h>

#define B 16
#define S 200
#define IN 128
#define H 128
#define NK 11      // K+1 buckets
#define OUTN 10000
#define H4 512

// ---------------- proj GEMMs (embed fused): P[r,kb,:] = table[seq[r],:] @ W[kb] ----------------
__global__ __launch_bounds__(512) void k_proj(
        const int* __restrict__ seq, const float* __restrict__ table,
        const int* __restrict__ length,
        const float* __restrict__ tw, const float* __restrict__ dw,
        float* __restrict__ pt, float* __restrict__ pd) {
    __shared__ float xs[32][68];    // [k][r], padded so xs[k][4*tr] is 16B aligned
    __shared__ float wsm[32][128];  // [k][c]
    __shared__ int sneed;
    int tid = threadIdx.x;
    int r0blk = blockIdx.x * 64;
    if (tid == 0) sneed = 0;
    __syncthreads();
    if (tid < 64) {
        int r = r0blk + tid;
        int bb = r / S, ii = r - bb * S;
        if (ii < length[bb]) sneed = 1;   // benign same-value race
    }
    __syncthreads();
    if (!sneed) return;

    int which = blockIdx.y / NK;
    int kb = blockIdx.y % NK;
    const float* W = (which == 0 ? tw : dw) + kb * IN * H;
    float* P = (which == 0 ? pt : pd);
    int tr = tid >> 5;          // 0..15 (row group)
    int tc = tid & 31;          // 0..31 (col group)
    int rr0 = tr * 4;

    float acc[4][4] = {{0.f}};
    for (int kk = 0; kk < IN; kk += 32) {
        {   // load x tile via embed gather (transposed into xs[k][r])
            int r = tid >> 3;              // 0..63
            int kq = (tid & 7) * 4;        // 0,4,..,28
            int sv = seq[r0blk + r];
            float4 v = *reinterpret_cast<const float4*>(&table[sv * IN + kk + kq]);
            xs[kq + 0][r] = v.x; xs[kq + 1][r] = v.y;
            xs[kq + 2][r] = v.z; xs[kq + 3][r] = v.w;
        }
        #pragma unroll
        for (int i = 0; i < 2; ++i) {       // load W chunk [32][128]
            int f = tid + i * 512;          // float4 index 0..1023
            int k = f >> 5; int c4 = f & 31;
            *reinterpret_cast<float4*>(&wsm[k][c4 * 4]) =
                *reinterpret_cast<const float4*>(&W[(kk + k) * H + c4 * 4]);
        }
        __syncthreads();
        #pragma unroll
        for (int k = 0; k < 32; ++k) {
            float4 a = *reinterpret_cast<const float4*>(&xs[k][rr0]);
            float4 w = *reinterpret_cast<const float4*>(&wsm[k][tc * 4]);
            acc[0][0] += a.x * w.x; acc[0][1] += a.x * w.y; acc[0][2] += a.x * w.z; acc[0][3] += a.x * w.w;
            acc[1][0] += a.y * w.x; acc[1][1] += a.y * w.y; acc[1][2] += a.y * w.z; acc[1][3] += a.y * w.w;
            acc[2][0] += a.z * w.x; acc[2][1] += a.z * w.y; acc[2][2] += a.z * w.z; acc[2][3] += a.z * w.w;
            acc[3][0] += a.w * w.x; acc[3][1] += a.w * w.y; acc[3][2] += a.w * w.z; acc[3][3] += a.w * w.w;
        }
        __syncthreads();
    }
    #pragma unroll
    for (int i = 0; i < 4; ++i) {
        int r = r0blk + rr0 + i;
        float4 v = make_float4(acc[i][0], acc[i][1], acc[i][2], acc[i][3]);
        *reinterpret_cast<float4*>(&P[(r * NK + kb) * H + tc * 4]) = v;
    }
}

// ---------------- X[b,i,:] = 0.5 * sum_j (P_t[b,j,tk] + P_d[b,j,dk]) ----------------
__global__ __launch_bounds__(512) void k_xsum(const float* __restrict__ pt, const float* __restrict__ pd,
                       const int* __restrict__ length, const float* __restrict__ ts,
                       const float* __restrict__ lat, const float* __restrict__ lng,
                       float* __restrict__ X) {
    int wg = blockIdx.x;
    int idx = wg >> 3;                    // 0..399
    int b = (wg & 7) + 8 * (idx / S);     // XCD x serves batches {x, x+8}: L2 locality
    int i = idx % S;
    int len = length[b];
    if (i >= len) return;
    __shared__ float sts[S], sla[S], sln[S];
    __shared__ float psum[16][128];
    int tid = threadIdx.x;
    int jg = tid >> 5, c = tid & 31;
    if (tid < S) {
        sts[tid] = ts[b * S + tid]; sla[tid] = lat[b * S + tid]; sln[tid] = lng[b * S + tid];
    }
    __syncthreads();
    float ti = sts[i], lai = sla[i], lni = sln[i];
    float4 at = make_float4(0.f, 0.f, 0.f, 0.f);
    float4 ad = make_float4(0.f, 0.f, 0.f, 0.f);
    const float* ptb = pt + (b * S) * NK * H;
    const float* pdb = pd + (b * S) * NK * H;
    for (int j = jg; j <= i; j += 16) {       // interleaved for group load balance
        float td = ti - sts[j];
        if (td < 0.f || td > 1.f) continue;   // exact reference window
        int tk = (int)(td * 10.f); if (tk > 10) tk = 10;    // td>=0: cast==floor
        float dx = lai - sla[j], dy = lni - sln[j];
        float dist = sqrtf(dx * dx + dy * dy);
        int dk = (int)(dist * 10.f); if (dk > 10) dk = 10;  // matches clip->*10->floor
        float4 vt = *((const float4*)&ptb[(j * NK + tk) * H] + c);
        float4 vd = *((const float4*)&pdb[(j * NK + dk) * H] + c);
        at.x += vt.x; at.y += vt.y; at.z += vt.z; at.w += vt.w;
        ad.x += vd.x; ad.y += vd.y; ad.z += vd.z; ad.w += vd.w;
    }
    float4 s4 = make_float4(at.x + ad.x, at.y + ad.y, at.z + ad.z, at.w + ad.w);
    *reinterpret_cast<float4*>(&psum[jg][c * 4]) = s4;
    __syncthreads();
    if (tid < H) {
        float s = 0.f;
        #pragma unroll
        for (int g = 0; g < 16; ++g) s += psum[g][tid];
        X[(b * S + i) * H + tid] = 0.5f * s;
    }
}

// ---------------- RNN + fused FC1 ----------------
// grid B, block 512 (8 waves). X[b] (102.4 KB) staged fully into LDS up front, so the
// in-loop X read is an LDS read issued at loop top and consumed at loop end (hidden).
// lane = oo*4+kg, o = wave*16+oo; 4-way k-split, 2x shfl_xor reduce; ping-pong h; one barrier/step.
// Tail computes t1[b,:] = tanh(h_final @ W1 + b1) (fc1 fused: h_final already in LDS).
__global__ __launch_bounds__(512) void k_rnn(const float* __restrict__ X,
        const float* __restrict__ Wh, const int* __restrict__ length,
        const float* __restrict__ W1, const float* __restrict__ b1,
        float* __restrict__ t1) {
    __shared__ float xlds[S * H];     // 100 KB
    __shared__ float hbuf[2][H];
    int b = blockIdx.x;
    int len = length[b];
    int tid = threadIdx.x;
    int w8 = tid >> 6;          // wave 0..7
    int lane = tid & 63;
    int oo = lane >> 2;         // 0..15
    int kg = lane & 3;          // 0..3
    int o = w8 * 16 + oo;       // output index 0..127
    float wreg[32];
    #pragma unroll
    for (int it = 0; it < 8; ++it) {
        int kk = kg * 32 + ((it ^ kg) & 7) * 4;
        #pragma unroll
        for (int q = 0; q < 4; ++q)
            wreg[it * 4 + q] = Wh[(kk + q) * H + o];
    }
    {   // stage X[b] -> LDS (fully parallel, coalesced float4)
        const float4* Xb4 = reinterpret_cast<const float4*>(X + b * S * H);
        float4* xl4 = reinterpret_cast<float4*>(xlds);
        for (int idx = tid; idx < S * H / 4; idx += 512) xl4[idx] = Xb4[idx];
    }
    if (tid < H) hbuf[0][tid] = 0.f;
    __syncthreads();
    int cur = 0;
    for (int i = 0; i < len; ++i) {
        float xc = xlds[i * H + o];          // LDS read, hidden under the FMA chain
        const float* hb = &hbuf[cur][kg * 32];
        float p0 = 0.f, p1 = 0.f, p2 = 0.f, p3 = 0.f;
        #pragma unroll
        for (int it = 0; it < 8; ++it) {
            float4 hv = *reinterpret_cast<const float4*>(&hb[((it ^ kg) & 7) * 4]);
            p0 += hv.x * wreg[it * 4 + 0];
            p1 += hv.y * wreg[it * 4 + 1];
            p2 += hv.z * wreg[it * 4 + 2];
            p3 += hv.w * wreg[it * 4 + 3];
        }
        float p = (p0 + p1) + (p2 + p3);
        p += __shfl_xor(p, 1);
        p += __shfl_xor(p, 2);
        if (kg == 0) {
            float hn = 1.f / (1.f + __expf(-(xc + p)));
            hbuf[cur ^ 1][o] = hn;
        }
        __syncthreads();
        cur ^= 1;
    }
    // fused fc1: t1[b,o512] = tanh(b1 + sum_k h_final[k] * W1[k][o512])
    const float* hfin = hbuf[cur];
    float acc = b1[tid];
    #pragma unroll 4
    for (int k = 0; k < H; ++k) acc += hfin[k] * W1[k * H4 + tid];
    t1[b * H4 + tid] = tanhf(acc);
}

// ---------------- FC2: out[b,o] = t1[b,:] @ W2[:,o] + b2[o] ----------------
__global__ __launch_bounds__(256) void k_fc2(const float* __restrict__ t1,
        const float* __restrict__ W2, const float* __restrict__ b2,
        float* __restrict__ out) {
    __shared__ float tls[H4 * B];   // [k][b] layout, 32KB
    int tid = threadIdx.x;
    int o = blockIdx.x * 64 + (tid & 63);
    int bq = tid >> 6;              // 0..3
    for (int idx = tid; idx < H4 * B; idx += 256) {
        int k = idx >> 4, bb = idx & 15;
        tls[idx] = t1[bb * H4 + k];
    }
    __syncthreads();
    if (o >= OUTN) return;
    float a0 = 0.f, a1 = 0.f, a2 = 0.f, a3 = 0.f;
    for (int k = 0; k < H4; ++k) {
        float wv = W2[k * OUTN + o];
        const float* tk = &tls[k * 16 + bq * 4];
        a0 += wv * tk[0]; a1 += wv * tk[1]; a2 += wv * tk[2]; a3 += wv * tk[3];
    }
    float bb2 = b2[o];
    out[(bq * 4 + 0) * OUTN + o] = a0 + bb2;
    out[(bq * 4 + 1) * OUTN + o] = a1 + bb2;
    out[(bq * 4 + 2) * OUTN + o] = a2 + bb2;
    out[(bq * 4 + 3) * OUTN + o] = a3 + bb2;
}

extern "C" void kernel_launch(void* const* d_in, const int* in_sizes, int n_in,
                              void* d_out, int out_size, void* d_ws, size_t ws_size,
                              hipStream_t stream) {
    const int*   seq    = (const int*)d_in[0];
    const int*   length = (const int*)d_in[1];
    const float* ts     = (const float*)d_in[2];
    const float* lat    = (const float*)d_in[3];
    const float* lng    = (const float*)d_in[4];
    const float* table  = (const float*)d_in[5];
    const float* tw     = (const float*)d_in[6];
    const float* dw     = (const float*)d_in[7];
    const float* wh     = (const float*)d_in[8];
    const float* W1     = (const float*)d_in[9];
    const float* b1     = (const float*)d_in[10];
    const float* W2     = (const float*)d_in[11];
    const float* b2     = (const float*)d_in[12];
    float* out = (float*)d_out;

    float* wsf  = (float*)d_ws;
    float* pt   = wsf;                       // B*S*NK*H = 4505600
    float* pd   = pt + B * S * NK * H;       // B*S*NK*H = 4505600
    float* X    = pd + B * S * NK * H;       // B*S*H    = 409600
    float* t1   = X  + B * S * H;            // B*H4     = 8192

    k_proj<<<dim3((B * S) / 64, 2 * NK), 512, 0, stream>>>(seq, table, length, tw, dw, pt, pd);
    k_xsum<<<B * S, 512, 0, stream>>>(pt, pd, length, ts, lat, lng, X);
    k_rnn<<<B, 512, 0, stream>>>(X, wh, length, W1, b1, t1);
    k_fc2<<<(OUTN + 63) / 64, 256, 0, stream>>>(t1, W2, b2, out);
}